// Round 1
// baseline (253.531 us; speedup 1.0000x reference)
//
#include <hip/hip_runtime.h>
#include <hip/hip_bf16.h>

typedef __attribute__((ext_vector_type(8))) __bf16 bf16x8;
typedef __attribute__((ext_vector_type(16))) float f32x16;

#define NB 16
#define NROW 2048
#define ND 256
#define NTOT (NB * NROW)            // 32768 rows total per tensor
#define CHUNKS_PER_BATCH 65536      // 2048*256 bf16 / 8 per 16B chunk
#define SCALE_L2E 14.4269504088896f // 10 * log2(e)

// ---------------------------------------------------------------------------
// bf16 pack helpers (RNE)
// ---------------------------------------------------------------------------
__device__ inline unsigned int f2bf(float f) {
    unsigned int u = __builtin_bit_cast(unsigned int, f);
    u += 0x7fffu + ((u >> 16) & 1u);
    return u >> 16;
}

__device__ inline uint4 pack8(float4 x, float4 y, float s) {
    uint4 r;
    r.x = f2bf(x.x * s) | (f2bf(x.y * s) << 16);
    r.y = f2bf(x.z * s) | (f2bf(x.w * s) << 16);
    r.z = f2bf(y.x * s) | (f2bf(y.y * s) << 16);
    r.w = f2bf(y.z * s) | (f2bf(y.w * s) << 16);
    return r;
}

// ---------------------------------------------------------------------------
// Kernel 1: L2-normalize A and B rows -> bf16 in MFMA-fragment-major layout,
// plus exact fp32 diagonal accumulation: diag = dot(a,b)/(|a||b|) * 10.
//
// Fragment-major layout per batch: 16B chunk index =
//   (mt*16 + kt)*64 + (m&31) + 32*khalf,  mt = row>>5, kt = col>>4,
//   khalf = (col>>3)&1, within-chunk j = col&7.
// This makes GEMM lane l's A/B-frag load = chunk base + l (coalesced 1KB).
// ---------------------------------------------------------------------------
__global__ __launch_bounds__(256) void nrm_kernel(
        const float* __restrict__ A, const float* __restrict__ B,
        uint4* __restrict__ E1f, uint4* __restrict__ E2f,
        float* __restrict__ diagSum) {
    __shared__ float sdiag;
    const int tid = threadIdx.x;
    if (tid == 0) sdiag = 0.f;
    __syncthreads();

    const int w = tid >> 6, l = tid & 63, q = l & 31;
    const int n0 = (blockIdx.x * 4 + w) * 2 + (l >> 5);  // global row 0..32767

    const float4* A4 = (const float4*)A + (size_t)n0 * 64 + q * 2;
    const float4* B4 = (const float4*)B + (size_t)n0 * 64 + q * 2;
    float4 a0 = A4[0], a1 = A4[1];
    float4 b0 = B4[0], b1 = B4[1];

    float sa = a0.x*a0.x + a0.y*a0.y + a0.z*a0.z + a0.w*a0.w
             + a1.x*a1.x + a1.y*a1.y + a1.z*a1.z + a1.w*a1.w;
    float sb = b0.x*b0.x + b0.y*b0.y + b0.z*b0.z + b0.w*b0.w
             + b1.x*b1.x + b1.y*b1.y + b1.z*b1.z + b1.w*b1.w;
    float dd = a0.x*b0.x + a0.y*b0.y + a0.z*b0.z + a0.w*b0.w
             + a1.x*b1.x + a1.y*b1.y + a1.z*b1.z + a1.w*b1.w;

    #pragma unroll
    for (int off = 1; off <= 16; off <<= 1) {
        sa += __shfl_xor(sa, off, 32);
        sb += __shfl_xor(sb, off, 32);
        dd += __shfl_xor(dd, off, 32);
    }
    const float ia = 1.0f / fmaxf(sqrtf(sa), 1e-12f);
    const float ib = 1.0f / fmaxf(sqrtf(sb), 1e-12f);
    if (q == 0) atomicAdd(&sdiag, dd * ia * ib * 10.0f);

    const int b  = n0 >> 11, n = n0 & 2047;
    const int mt = n >> 5, m_in = n & 31;
    const int kt = q >> 1, kh = q & 1;
    const size_t chunk = (size_t)b * CHUNKS_PER_BATCH
                       + (size_t)(mt * 16 + kt) * 64 + m_in + 32 * kh;
    E1f[chunk] = pack8(a0, a1, ia);
    E2f[chunk] = pack8(b0, b1, ib);

    __syncthreads();
    if (tid == 0) atomicAdd(diagSum, sdiag);
}

// ---------------------------------------------------------------------------
// Kernel 2: fused S = E1*E2^T (per batch), exp(s*10 - 10) accumulated into
// row sums (registers -> shuffle reduce) and column sums (LDS -> global).
// Block: 256 thr (4 waves), covers 64 rows x 2048 cols. Wave w: row group
// (w&1), column half (w>>1). grid = (32 row-tiles, 16 batches) = 512 blocks.
// A-frags live in registers (16 x bf16x8); B-frags stream from L1/L2.
// ---------------------------------------------------------------------------
__global__ __launch_bounds__(256) void gemm_kernel(
        const bf16x8* __restrict__ E1f, const bf16x8* __restrict__ E2f,
        float* __restrict__ colSum, float* __restrict__ rowLseSum) {
    __shared__ float colLDS[2048];
    __shared__ float rowLDS[64];

    const int tid = threadIdx.x, w = tid >> 6, l = tid & 63;
    const int b = blockIdx.y, rt = blockIdx.x;  // rt: 0..31 (64-row tiles)
    const int mt = rt * 2 + (w & 1);            // 32-row group for this wave
    const int colHalf = w >> 1;

    for (int i = tid; i < 2048; i += 256) colLDS[i] = 0.f;
    if (tid < 64) rowLDS[tid] = 0.f;
    __syncthreads();

    // A fragments: 32 rows x 256 K held in registers (64 VGPRs)
    const bf16x8* Af = E1f + (size_t)b * CHUNKS_PER_BATCH + (size_t)mt * 1024 + l;
    bf16x8 af[16];
    #pragma unroll
    for (int kt = 0; kt < 16; ++kt) af[kt] = Af[kt * 64];

    float rowAcc[16];
    #pragma unroll
    for (int r = 0; r < 16; ++r) rowAcc[r] = 0.f;

    const bf16x8* Bbase = E2f + (size_t)b * CHUNKS_PER_BATCH + l;

    for (int it = 0; it < 16; ++it) {
        const int nt = colHalf * 32 + it * 2;   // two 32-col groups per iter
        const bf16x8* B0 = Bbase + (size_t)nt * 1024;
        const bf16x8* B1 = B0 + 1024;

        f32x16 acc0, acc1;
        #pragma unroll
        for (int r = 0; r < 16; ++r) { acc0[r] = 0.f; acc1[r] = 0.f; }

        #pragma unroll
        for (int kt = 0; kt < 16; ++kt) {
            bf16x8 bf0 = B0[kt * 64];
            bf16x8 bf1 = B1[kt * 64];
            acc0 = __builtin_amdgcn_mfma_f32_32x32x16_bf16(af[kt], bf0, acc0, 0, 0, 0);
            acc1 = __builtin_amdgcn_mfma_f32_32x32x16_bf16(af[kt], bf1, acc1, 0, 0, 0);
        }

        // epilogue: e = exp(s*10 - 10) = exp2(s*10*log2e - 10*log2e)
        float p0 = 0.f, p1 = 0.f;
        #pragma unroll
        for (int r = 0; r < 16; ++r) {
            float e0 = exp2f(fmaf(acc0[r], SCALE_L2E, -SCALE_L2E));
            float e1 = exp2f(fmaf(acc1[r], SCALE_L2E, -SCALE_L2E));
            rowAcc[r] += e0 + e1;
            p0 += e0; p1 += e1;
        }
        // fold the two 16-row halves (lanes l and l^32 share a column)
        p0 += __shfl_xor(p0, 32);
        p1 += __shfl_xor(p1, 32);
        if (l < 32) {
            const int c0 = nt * 32 + l;
            atomicAdd(&colLDS[c0], p0);
            atomicAdd(&colLDS[c0 + 32], p1);
        }
    }

    // row sums: reduce across the 32 column-lanes
    #pragma unroll
    for (int r = 0; r < 16; ++r) {
        #pragma unroll
        for (int off = 1; off <= 16; off <<= 1)
            rowAcc[r] += __shfl_xor(rowAcc[r], off, 32);
    }
    if ((l & 31) == 0) {
        #pragma unroll
        for (int r = 0; r < 16; ++r) {
            // C/D layout (HW-verified): row = (reg&3) + 8*(reg>>2) + 4*(lane>>5)
            const int row_local = (w & 1) * 32 + (r & 3) + 8 * (r >> 2) + 4 * (l >> 5);
            atomicAdd(&rowLDS[row_local], rowAcc[r]);
        }
    }
    __syncthreads();

    // block row-lse partial: sum of log(rowsum) over this block's 64 rows
    if (w == 0) {
        float s = logf(rowLDS[tid]);
        #pragma unroll
        for (int off = 1; off <= 32; off <<= 1) s += __shfl_xor(s, off, 64);
        if (l == 0) atomicAdd(rowLseSum, s);
    }

    // flush column partial sums
    float* gcol = colSum + (size_t)b * 2048;
    for (int i = tid; i < 2048; i += 256) atomicAdd(&gcol[i], colLDS[i]);
}

// ---------------------------------------------------------------------------
// Kernel 3: final reduction.
// out = (sum_rows log(rs) + sum_cols log(cs) - 2*diagSum)/32768 + 2*10
// (the +10 fixed-max per lse, both directions -> +20 total)
// ---------------------------------------------------------------------------
__global__ __launch_bounds__(256) void fin_kernel(
        const float* __restrict__ colSum, const float* __restrict__ scalars,
        float* __restrict__ out) {
    const int tid = threadIdx.x;
    float s = 0.f;
    for (int i = tid; i < NTOT; i += 256) s += logf(colSum[i]);
    #pragma unroll
    for (int off = 1; off <= 32; off <<= 1) s += __shfl_xor(s, off, 64);
    __shared__ float red[4];
    if ((tid & 63) == 0) red[tid >> 6] = s;
    __syncthreads();
    if (tid == 0) {
        const float colL = red[0] + red[1] + red[2] + red[3];
        out[0] = (scalars[0] + colL - 2.0f * scalars[1]) / (float)NTOT + 20.0f;
    }
}

// ---------------------------------------------------------------------------
extern "C" void kernel_launch(void* const* d_in, const int* in_sizes, int n_in,
                              void* d_out, int out_size, void* d_ws, size_t ws_size,
                              hipStream_t stream) {
    const float* A = (const float*)d_in[0];
    const float* B = (const float*)d_in[1];

    char* w = (char*)d_ws;
    uint4* E1f = (uint4*)w;                                   // 16 MB
    uint4* E2f = (uint4*)(w + (size_t)16 * 1024 * 1024);      // 16 MB
    float* colSum = (float*)(w + (size_t)32 * 1024 * 1024);   // 128 KB
    float* scalars = colSum + NTOT;                           // [rowLseSum, diagSum]

    hipMemsetAsync(colSum, 0, (size_t)NTOT * 4 + 8, stream);

    hipLaunchKernelGGL(nrm_kernel, dim3(4096), dim3(256), 0, stream,
                       A, B, E1f, E2f, scalars + 1);
    hipLaunchKernelGGL(gemm_kernel, dim3(32, 16), dim3(256), 0, stream,
                       (const bf16x8*)E1f, (const bf16x8*)E2f, colSum, scalars);
    hipLaunchKernelGGL(fin_kernel, dim3(1), dim3(256), 0, stream,
                       colSum, scalars, (float*)d_out);
}

// Round 2
// 190.584 us; speedup vs baseline: 1.3303x; 1.3303x over previous
//
#include <hip/hip_runtime.h>
#include <hip/hip_bf16.h>

typedef __attribute__((ext_vector_type(8))) __bf16 bf16x8;
typedef __attribute__((ext_vector_type(16))) float f32x16;

#define CHUNKS_PER_BATCH 65536      // 2048*256 bf16 / 8 per 16B chunk
#define SCALE_L2E 14.4269504088896f // 10 * log2(e)
#define NTOT 32768

#define AS_GLOBAL __attribute__((address_space(1)))
#define AS_LDS    __attribute__((address_space(3)))

__device__ inline void async_copy16(const void* g, void* l) {
    __builtin_amdgcn_global_load_lds((const AS_GLOBAL void*)g, (AS_LDS void*)l, 16, 0, 0);
}

// ---------------------------------------------------------------------------
// bf16 pack helpers (RNE)
// ---------------------------------------------------------------------------
__device__ inline unsigned int f2bf(float f) {
    unsigned int u = __builtin_bit_cast(unsigned int, f);
    u += 0x7fffu + ((u >> 16) & 1u);
    return u >> 16;
}

__device__ inline uint4 pack8(float4 x, float4 y, float s) {
    uint4 r;
    r.x = f2bf(x.x * s) | (f2bf(x.y * s) << 16);
    r.y = f2bf(x.z * s) | (f2bf(x.w * s) << 16);
    r.z = f2bf(y.x * s) | (f2bf(y.y * s) << 16);
    r.w = f2bf(y.z * s) | (f2bf(y.w * s) << 16);
    return r;
}

// ---------------------------------------------------------------------------
// Kernel 1: L2-normalize -> bf16 fragment-major layout + exact fp32 diag.
// Scatter goes through LDS (pad 9 chunks/q-row -> conflict-free b128);
// global stores are 128 B-contiguous runs (full cachelines).
// Block: 256 thr, 8 rows. Grid 4096.
// ---------------------------------------------------------------------------
__global__ __launch_bounds__(256) void nrm_kernel(
        const float* __restrict__ A, const float* __restrict__ B,
        uint4* __restrict__ E1f, uint4* __restrict__ E2f,
        float* __restrict__ diagSum) {
    __shared__ uint4 sA[288], sB[288];   // 32 q-rows * 9 (8 used + 1 pad)
    __shared__ float sdiag;
    const int tid = threadIdx.x;
    if (tid == 0) sdiag = 0.f;
    __syncthreads();

    const int w = tid >> 6, l = tid & 63, q = l & 31;
    const int r = w * 2 + (l >> 5);          // local row 0..7
    const int n0 = blockIdx.x * 8 + r;       // global row 0..32767

    const float4* A4 = (const float4*)A + (size_t)n0 * 64 + q * 2;
    const float4* B4 = (const float4*)B + (size_t)n0 * 64 + q * 2;
    float4 a0 = A4[0], a1 = A4[1];
    float4 b0 = B4[0], b1 = B4[1];

    float sa = a0.x*a0.x + a0.y*a0.y + a0.z*a0.z + a0.w*a0.w
             + a1.x*a1.x + a1.y*a1.y + a1.z*a1.z + a1.w*a1.w;
    float sb = b0.x*b0.x + b0.y*b0.y + b0.z*b0.z + b0.w*b0.w
             + b1.x*b1.x + b1.y*b1.y + b1.z*b1.z + b1.w*b1.w;
    float dd = a0.x*b0.x + a0.y*b0.y + a0.z*b0.z + a0.w*b0.w
             + a1.x*b1.x + a1.y*b1.y + a1.z*b1.z + a1.w*b1.w;

    #pragma unroll
    for (int off = 1; off <= 16; off <<= 1) {
        sa += __shfl_xor(sa, off, 32);
        sb += __shfl_xor(sb, off, 32);
        dd += __shfl_xor(dd, off, 32);
    }
    const float ia = 1.0f / fmaxf(sqrtf(sa), 1e-12f);
    const float ib = 1.0f / fmaxf(sqrtf(sb), 1e-12f);
    if (q == 0) atomicAdd(&sdiag, dd * ia * ib * 10.0f);

    const int idxL = q * 9 + r;
    sA[idxL] = pack8(a0, a1, ia);
    sB[idxL] = pack8(b0, b1, ib);
    __syncthreads();

    // copy-out: thread i -> chunk (kt = i>>4, kh = (i>>3)&1, rr = i&7)
    const int kt = tid >> 4, kh = (tid >> 3) & 1, rr = tid & 7;
    const int qq = tid >> 3;                 // 2*kt + kh
    const int nb = blockIdx.x * 8;
    const int b = nb >> 11, n = nb & 2047;
    const int mt = n >> 5, m0 = n & 31;
    const size_t g = (size_t)b * CHUNKS_PER_BATCH
                   + (size_t)(mt * 16 + kt) * 64 + kh * 32 + m0 + rr;
    const int srcIdx = qq * 9 + rr;
    E1f[g] = sA[srcIdx];
    E2f[g] = sB[srcIdx];

    if (tid == 0) atomicAdd(diagSum, sdiag);
}

// ---------------------------------------------------------------------------
// Kernel 2: fused GEMM + exp + row/col accumulation.
// Grid (rt=16, ct=4, b=16) = 1024 blocks. Block: 4 waves, 128 rows x 512 cols.
// Wave w: rows rt*128 + w*32 (A-frags in 64 VGPRs), all 512 cols.
// B col-groups (32 cols x 256 K = 16 KB) staged via global_load_lds,
// double-buffered; all 4 waves consume each stage.
// ---------------------------------------------------------------------------
__global__ __launch_bounds__(256, 4) void gemm_kernel(
        const bf16x8* __restrict__ E1f, const uint4* __restrict__ E2f,
        float* __restrict__ colSum, float* __restrict__ rowSum) {
    __shared__ bf16x8 Bbuf[2][1024];   // 2 x 16 KB
    __shared__ float colLDS[512];

    const int tid = threadIdx.x, w = tid >> 6, l = tid & 63;
    const int rt = blockIdx.x, ct = blockIdx.y, b = blockIdx.z;

    for (int i = tid; i < 512; i += 256) colLDS[i] = 0.f;

    // A fragments: 32 rows x 256 K in registers
    const bf16x8* Af = E1f + (size_t)b * CHUNKS_PER_BATCH
                     + (size_t)(rt * 4 + w) * 1024 + l;
    bf16x8 af[16];
    #pragma unroll
    for (int kt = 0; kt < 16; ++kt) af[kt] = Af[kt * 64];

    float rowAcc[16];
    #pragma unroll
    for (int r = 0; r < 16; ++r) rowAcc[r] = 0.f;

    // B chunk base for this block's col range
    const uint4* Bb = E2f + (size_t)b * CHUNKS_PER_BATCH + (size_t)ct * 16384 + l;

    // stage col-group cg into Bbuf[buf]: wave w stages kt = w*4 .. w*4+3
    auto stage = [&](int buf, int cg) {
        const uint4* src = Bb + (size_t)cg * 1024 + (w * 4) * 64;
        #pragma unroll
        for (int j = 0; j < 4; ++j)
            async_copy16(src + j * 64, &Bbuf[buf][(w * 4 + j) * 64]);
    };

    stage(0, 0);
    __syncthreads();

    for (int cg = 0; cg < 16; ++cg) {
        if (cg < 15) stage((cg + 1) & 1, cg + 1);

        const bf16x8* Bf = Bbuf[cg & 1];
        f32x16 acc;
        #pragma unroll
        for (int r = 0; r < 16; ++r) acc[r] = 0.f;

        #pragma unroll
        for (int kt = 0; kt < 16; ++kt)
            acc = __builtin_amdgcn_mfma_f32_32x32x16_bf16(af[kt], Bf[kt * 64 + l], acc, 0, 0, 0);

        // epilogue: e = exp(10*s - 10)
        float p = 0.f;
        #pragma unroll
        for (int r = 0; r < 16; ++r) {
            float e = exp2f(fmaf(acc[r], SCALE_L2E, -SCALE_L2E));
            rowAcc[r] += e;
            p += e;
        }
        p += __shfl_xor(p, 32);                 // fold two 16-row halves
        if (l < 32) atomicAdd(&colLDS[cg * 32 + l], p);
        __syncthreads();
    }

    // row sums: reduce across 32 column-lanes
    #pragma unroll
    for (int r = 0; r < 16; ++r) {
        #pragma unroll
        for (int off = 1; off <= 16; off <<= 1)
            rowAcc[r] += __shfl_xor(rowAcc[r], off);
    }
    if ((l & 31) == 0) {
        // C/D layout: row = (r&3) + 8*(r>>2) + 4*(lane>>5)
        float* rs = rowSum + (size_t)b * 2048 + rt * 128 + w * 32 + 4 * (l >> 5);
        #pragma unroll
        for (int r = 0; r < 16; ++r)
            atomicAdd(&rs[(r & 3) + 8 * (r >> 2)], rowAcc[r]);
    }

    // flush column partial sums (last loop barrier already synced colLDS)
    float* gcol = colSum + (size_t)b * 2048 + ct * 512;
    for (int i = tid; i < 512; i += 256) atomicAdd(&gcol[i], colLDS[i]);
}

// ---------------------------------------------------------------------------
// Kernel 3a: sum of log over the 65536 row+col sums (colSum||rowSum buffer).
// ---------------------------------------------------------------------------
__global__ __launch_bounds__(256) void fin1_kernel(
        const float* __restrict__ red, float* __restrict__ scalars) {
    const int tid = threadIdx.x;
    float s = 0.f;
    #pragma unroll
    for (int k = 0; k < 4; ++k)
        s += logf(red[blockIdx.x * 1024 + k * 256 + tid]);
    #pragma unroll
    for (int off = 1; off <= 32; off <<= 1) s += __shfl_xor(s, off);
    __shared__ float part[4];
    if ((tid & 63) == 0) part[tid >> 6] = s;
    __syncthreads();
    if (tid == 0)
        atomicAdd(&scalars[0], part[0] + part[1] + part[2] + part[3]);
}

// ---------------------------------------------------------------------------
// Kernel 3b: out = (sum_logs - 2*diag)/32768 + 20   (fixed-max 10 per lse x2)
// ---------------------------------------------------------------------------
__global__ void fin2_kernel(const float* __restrict__ scalars,
                            float* __restrict__ out) {
    out[0] = (scalars[0] - 2.0f * scalars[1]) / (float)NTOT + 20.0f;
}

// ---------------------------------------------------------------------------
extern "C" void kernel_launch(void* const* d_in, const int* in_sizes, int n_in,
                              void* d_out, int out_size, void* d_ws, size_t ws_size,
                              hipStream_t stream) {
    const float* A = (const float*)d_in[0];
    const float* B = (const float*)d_in[1];

    char* w = (char*)d_ws;
    uint4* E1f = (uint4*)w;                                   // 16 MB
    uint4* E2f = (uint4*)(w + (size_t)16 * 1024 * 1024);      // 16 MB
    float* colSum = (float*)(w + (size_t)32 * 1024 * 1024);   // 32768 f
    float* rowSum = colSum + NTOT;                            // 32768 f
    float* scalars = rowSum + NTOT;                           // [logSum, diag]

    hipMemsetAsync(colSum, 0, (size_t)(2 * NTOT + 2) * 4, stream);

    hipLaunchKernelGGL(nrm_kernel, dim3(4096), dim3(256), 0, stream,
                       A, B, E1f, E2f, scalars + 1);
    hipLaunchKernelGGL(gemm_kernel, dim3(16, 4, 16), dim3(256), 0, stream,
                       (const bf16x8*)E1f, (const uint4*)E2f, colSum, rowSum);
    hipLaunchKernelGGL(fin1_kernel, dim3(64), dim3(256), 0, stream,
                       colSum, scalars);
    hipLaunchKernelGGL(fin2_kernel, dim3(1), dim3(1), 0, stream,
                       scalars, (float*)d_out);
}

// Round 3
// 160.961 us; speedup vs baseline: 1.5751x; 1.1840x over previous
//
#include <hip/hip_runtime.h>
#include <hip/hip_bf16.h>

typedef __attribute__((ext_vector_type(8))) __bf16 bf16x8;
typedef __attribute__((ext_vector_type(16))) float f32x16;

#define SCALE_L2E 14.4269504088896f // 10 * log2(e)
#define NTOT 32768

#define AS_GLOBAL __attribute__((address_space(1)))
#define AS_LDS    __attribute__((address_space(3)))

__device__ inline void async_copy16(const void* g, void* l) {
    __builtin_amdgcn_global_load_lds((const AS_GLOBAL void*)g, (AS_LDS void*)l, 16, 0, 0);
}

// ---------------------------------------------------------------------------
// bf16 pack helpers (RNE)
// ---------------------------------------------------------------------------
__device__ inline unsigned int f2bf(float f) {
    unsigned int u = __builtin_bit_cast(unsigned int, f);
    u += 0x7fffu + ((u >> 16) & 1u);
    return u >> 16;
}

__device__ inline uint4 pack8(float4 x, float4 y, float s) {
    uint4 r;
    r.x = f2bf(x.x * s) | (f2bf(x.y * s) << 16);
    r.y = f2bf(x.z * s) | (f2bf(x.w * s) << 16);
    r.z = f2bf(y.x * s) | (f2bf(y.y * s) << 16);
    r.w = f2bf(y.z * s) | (f2bf(y.w * s) << 16);
    return r;
}

// ---------------------------------------------------------------------------
// Kernel 1: L2-normalize -> bf16 ROW-MAJOR + exact fp32 diag per block.
// No LDS transpose, no global atomics. Wave = 2 rows; store = contiguous 1KB.
// ---------------------------------------------------------------------------
__global__ __launch_bounds__(256) void nrm_kernel(
        const float* __restrict__ A, const float* __restrict__ B,
        uint4* __restrict__ E1, uint4* __restrict__ E2,
        float* __restrict__ diagPart) {
    __shared__ float sdiag;
    const int tid = threadIdx.x;
    if (tid == 0) sdiag = 0.f;
    __syncthreads();

    const int w = tid >> 6, l = tid & 63, q = l & 31, h = l >> 5;
    const int n0 = blockIdx.x * 8 + w * 2 + h;   // global row

    const float4* A4 = (const float4*)A + (size_t)n0 * 64 + q * 2;
    const float4* B4 = (const float4*)B + (size_t)n0 * 64 + q * 2;
    float4 a0 = A4[0], a1 = A4[1];
    float4 b0 = B4[0], b1 = B4[1];

    float sa = a0.x*a0.x + a0.y*a0.y + a0.z*a0.z + a0.w*a0.w
             + a1.x*a1.x + a1.y*a1.y + a1.z*a1.z + a1.w*a1.w;
    float sb = b0.x*b0.x + b0.y*b0.y + b0.z*b0.z + b0.w*b0.w
             + b1.x*b1.x + b1.y*b1.y + b1.z*b1.z + b1.w*b1.w;
    float dd = a0.x*b0.x + a0.y*b0.y + a0.z*b0.z + a0.w*b0.w
             + a1.x*b1.x + a1.y*b1.y + a1.z*b1.z + a1.w*b1.w;

    #pragma unroll
    for (int off = 1; off <= 16; off <<= 1) {
        sa += __shfl_xor(sa, off, 32);
        sb += __shfl_xor(sb, off, 32);
        dd += __shfl_xor(dd, off, 32);
    }
    const float ia = 1.0f / fmaxf(sqrtf(sa), 1e-12f);
    const float ib = 1.0f / fmaxf(sqrtf(sb), 1e-12f);
    if (q == 0) atomicAdd(&sdiag, dd * ia * ib * 10.0f);

    E1[(size_t)n0 * 32 + q] = pack8(a0, a1, ia);
    E2[(size_t)n0 * 32 + q] = pack8(b0, b1, ib);

    __syncthreads();
    if (tid == 0) diagPart[blockIdx.x] = sdiag;
}

// ---------------------------------------------------------------------------
// Kernel 2: fused GEMM + exp + row/col accumulation. Row-major E inputs.
// Grid (rt=16, ct=4, b=16) = 1024 blocks, 4 waves. 128 rows x 512 cols.
// A-frags: per-lane row-major gather into 64 VGPRs (L1 absorbs line reuse).
// B: scattered-address global_load_lds -> fragment-ordered LDS, dbuffered.
// ---------------------------------------------------------------------------
__global__ __launch_bounds__(256, 4) void gemm_kernel(
        const bf16x8* __restrict__ E1, const bf16x8* __restrict__ E2,
        float* __restrict__ colSum, float* __restrict__ rowSum) {
    __shared__ bf16x8 Bbuf[2][1024];   // 2 x 16 KB
    __shared__ float colLDS[2048];     // 4 per-wave slices of 512

    const int tid = threadIdx.x, w = tid >> 6, l = tid & 63;
    const int m = l & 31, ko = l >> 5;
    const int rt = blockIdx.x, ct = blockIdx.y, b = blockIdx.z;

    // zero this wave's column slice (no barrier needed: wave-private)
    for (int i = l; i < 512; i += 64) colLDS[w * 512 + i] = 0.f;

    // A fragments: rows rt*128 + w*32 (+m), all 256 K, row-major gather
    const bf16x8* Arow = E1 + ((size_t)b * 2048 + rt * 128 + w * 32 + m) * 32 + ko;
    bf16x8 af[16];
    #pragma unroll
    for (int kt = 0; kt < 16; ++kt) af[kt] = Arow[kt * 2];

    float rowAcc[16];
    #pragma unroll
    for (int r = 0; r < 16; ++r) rowAcc[r] = 0.f;

    // B row base: cols (rows of E2) = b*2048 + ct*512 + cg*32 + m
    const bf16x8* Brow = E2 + ((size_t)b * 2048 + ct * 512 + m) * 32 + ko;

    // stage col-group cg into Bbuf[buf]; wave w covers kt = w*4..w*4+3
    auto stage = [&](int buf, int cg) {
        const bf16x8* src = Brow + (size_t)cg * 32 * 32 + (w * 4) * 2;
        #pragma unroll
        for (int j = 0; j < 4; ++j)
            async_copy16(src + j * 2, &Bbuf[buf][(w * 4 + j) * 64]);
    };

    stage(0, 0);
    __syncthreads();

    for (int cg = 0; cg < 16; ++cg) {
        if (cg < 15) stage((cg + 1) & 1, cg + 1);

        const bf16x8* Bf = Bbuf[cg & 1];
        f32x16 acc;
        #pragma unroll
        for (int r = 0; r < 16; ++r) acc[r] = 0.f;

        #pragma unroll
        for (int kt = 0; kt < 16; ++kt)
            acc = __builtin_amdgcn_mfma_f32_32x32x16_bf16(af[kt], Bf[kt * 64 + l], acc, 0, 0, 0);

        // epilogue: e = exp(10*s - 10)
        float p = 0.f;
        #pragma unroll
        for (int r = 0; r < 16; ++r) {
            float e = exp2f(fmaf(acc[r], SCALE_L2E, -SCALE_L2E));
            rowAcc[r] += e;
            p += e;
        }
        p += __shfl_xor(p, 32);                 // fold two 16-row halves
        if (l < 32) colLDS[w * 512 + cg * 32 + l] += p;   // wave-private slice
        __syncthreads();
    }

    // row sums: reduce across 32 column-lanes
    #pragma unroll
    for (int r = 0; r < 16; ++r) {
        #pragma unroll
        for (int off = 1; off <= 16; off <<= 1)
            rowAcc[r] += __shfl_xor(rowAcc[r], off);
    }
    if ((l & 31) == 0) {
        // C/D layout: row = (r&3) + 8*(r>>2) + 4*(lane>>5)
        float* rs = rowSum + (size_t)b * 2048 + rt * 128 + w * 32 + 4 * (l >> 5);
        #pragma unroll
        for (int r = 0; r < 16; ++r)
            atomicAdd(&rs[(r & 3) + 8 * (r >> 2)], rowAcc[r]);
    }

    // flush column sums (final loop barrier already ordered colLDS writes)
    float* gcol = colSum + (size_t)b * 2048 + ct * 512;
    for (int i = tid; i < 512; i += 256) {
        float s = colLDS[i] + colLDS[512 + i] + colLDS[1024 + i] + colLDS[1536 + i];
        atomicAdd(&gcol[i], s);
    }
}

// ---------------------------------------------------------------------------
// Kernel 3a: sum of log over the 65536 row+col sums (colSum||rowSum buffer).
// ---------------------------------------------------------------------------
__global__ __launch_bounds__(256) void fin1_kernel(
        const float* __restrict__ red, float* __restrict__ scalars) {
    const int tid = threadIdx.x;
    float s = 0.f;
    #pragma unroll
    for (int k = 0; k < 4; ++k)
        s += logf(red[blockIdx.x * 1024 + k * 256 + tid]);
    #pragma unroll
    for (int off = 1; off <= 32; off <<= 1) s += __shfl_xor(s, off);
    __shared__ float part[4];
    if ((tid & 63) == 0) part[tid >> 6] = s;
    __syncthreads();
    if (tid == 0)
        atomicAdd(&scalars[0], part[0] + part[1] + part[2] + part[3]);
}

// ---------------------------------------------------------------------------
// Kernel 3b: reduce diagPart + finalize.
// out = (sum_logs - 2*diag)/32768 + 20   (fixed-max 10 per lse x 2 dirs)
// ---------------------------------------------------------------------------
__global__ __launch_bounds__(256) void fin2_kernel(
        const float* __restrict__ diagPart, const float* __restrict__ scalars,
        float* __restrict__ out) {
    const int tid = threadIdx.x;
    float d = 0.f;
    for (int i = tid; i < 4096; i += 256) d += diagPart[i];
    #pragma unroll
    for (int off = 1; off <= 32; off <<= 1) d += __shfl_xor(d, off);
    __shared__ float part[4];
    if ((tid & 63) == 0) part[tid >> 6] = d;
    __syncthreads();
    if (tid == 0) {
        const float diag = part[0] + part[1] + part[2] + part[3];
        out[0] = (scalars[0] - 2.0f * diag) / (float)NTOT + 20.0f;
    }
}

// ---------------------------------------------------------------------------
extern "C" void kernel_launch(void* const* d_in, const int* in_sizes, int n_in,
                              void* d_out, int out_size, void* d_ws, size_t ws_size,
                              hipStream_t stream) {
    const float* A = (const float*)d_in[0];
    const float* B = (const float*)d_in[1];

    char* w = (char*)d_ws;
    uint4* E1 = (uint4*)w;                                    // 16 MB
    uint4* E2 = (uint4*)(w + (size_t)16 * 1024 * 1024);       // 16 MB
    float* colSum = (float*)(w + (size_t)32 * 1024 * 1024);   // 32768 f
    float* rowSum = colSum + NTOT;                            // 32768 f
    float* scalars = rowSum + NTOT;                           // [logSum, diag]
    float* diagPart = scalars + 2;                            // 4096 f

    hipMemsetAsync(colSum, 0, (size_t)(2 * NTOT + 2) * 4, stream);

    hipLaunchKernelGGL(nrm_kernel, dim3(4096), dim3(256), 0, stream,
                       A, B, E1, E2, diagPart);
    hipLaunchKernelGGL(gemm_kernel, dim3(16, 4, 16), dim3(256), 0, stream,
                       (const bf16x8*)E1, (const bf16x8*)E2, colSum, rowSum);
    hipLaunchKernelGGL(fin1_kernel, dim3(64), dim3(256), 0, stream,
                       colSum, scalars);
    hipLaunchKernelGGL(fin2_kernel, dim3(1), dim3(256), 0, stream,
                       diagPart, scalars, (float*)d_out);
}

// Round 4
// 160.393 us; speedup vs baseline: 1.5807x; 1.0035x over previous
//
#include <hip/hip_runtime.h>
#include <hip/hip_bf16.h>

typedef __attribute__((ext_vector_type(8))) __bf16 bf16x8;
typedef __attribute__((ext_vector_type(16))) float f32x16;

#define SCALE_L2E 14.4269504088896f // 10 * log2(e)
#define NTOT 32768

#define AS_GLOBAL __attribute__((address_space(1)))
#define AS_LDS    __attribute__((address_space(3)))

__device__ inline void async_copy16(const void* g, void* l) {
    __builtin_amdgcn_global_load_lds((const AS_GLOBAL void*)g, (AS_LDS void*)l, 16, 0, 0);
}

// ---------------------------------------------------------------------------
// bf16 pack helpers (RNE)
// ---------------------------------------------------------------------------
__device__ inline unsigned int f2bf(float f) {
    unsigned int u = __builtin_bit_cast(unsigned int, f);
    u += 0x7fffu + ((u >> 16) & 1u);
    return u >> 16;
}

__device__ inline uint4 pack8(float4 x, float4 y, float s) {
    uint4 r;
    r.x = f2bf(x.x * s) | (f2bf(x.y * s) << 16);
    r.y = f2bf(x.z * s) | (f2bf(x.w * s) << 16);
    r.z = f2bf(y.x * s) | (f2bf(y.y * s) << 16);
    r.w = f2bf(y.z * s) | (f2bf(y.w * s) << 16);
    return r;
}

__device__ inline float sum8(float4 x, float4 y) {
    return x.x + x.y + x.z + x.w + y.x + y.y + y.z + y.w;
}
__device__ inline float dot8(float4 x, float4 y) {
    return x.x*y.x + x.y*y.y + x.z*y.z + x.w*y.w;
}

// ---------------------------------------------------------------------------
// Kernel 1: L2-normalize -> bf16 FRAGMENT-MAJOR layout + fp32 diag partials.
// Fragment-major chunk (16B) for row n, k-octet q:
//   b*65536 + ((n&2047)>>5)*1024 + (q>>1)*64 + (q&1)*32 + (n&31)
// Pipelined: 1024 blocks x 4 waves; each wave does 4 iterations of 2 rows,
// prefetching iteration i+1's loads while reducing iteration i.
// ---------------------------------------------------------------------------
__global__ __launch_bounds__(256) void nrm_kernel(
        const float* __restrict__ A, const float* __restrict__ B,
        uint4* __restrict__ E1f, uint4* __restrict__ E2f,
        float* __restrict__ diagPart) {
    const int tid = threadIdx.x, w = tid >> 6, l = tid & 63;
    const int q = l & 31, h = l >> 5;
    const int wid = blockIdx.x * 4 + w;            // 0..4095, 8 rows each

    const float4* A4 = (const float4*)A + ((size_t)wid * 8 + h) * 64 + q * 2;
    const float4* B4 = (const float4*)B + ((size_t)wid * 8 + h) * 64 + q * 2;

    float ddAcc = 0.f;
    float4 a0 = A4[0], a1 = A4[1], b0 = B4[0], b1 = B4[1];

    #pragma unroll
    for (int i = 0; i < 4; ++i) {
        float4 na0, na1, nb0, nb1;
        if (i < 3) {
            const float4* An = A4 + (i + 1) * 128;
            const float4* Bn = B4 + (i + 1) * 128;
            na0 = An[0]; na1 = An[1]; nb0 = Bn[0]; nb1 = Bn[1];
        }
        float sa = dot8(a0, a0) + dot8(a1, a1);
        float sb = dot8(b0, b0) + dot8(b1, b1);
        float dd = dot8(a0, b0) + dot8(a1, b1);
        #pragma unroll
        for (int off = 1; off <= 16; off <<= 1) {   // masks <32: stays in half
            sa += __shfl_xor(sa, off);
            sb += __shfl_xor(sb, off);
            dd += __shfl_xor(dd, off);
        }
        const float ia = 1.0f / fmaxf(sqrtf(sa), 1e-12f);
        const float ib = 1.0f / fmaxf(sqrtf(sb), 1e-12f);
        if (q == 0) ddAcc += dd * ia * ib * 10.0f;

        const int n0 = wid * 8 + i * 2 + h;
        const size_t chunk = (size_t)(n0 >> 11) * 65536
                           + (size_t)((n0 & 2047) >> 5) * 1024
                           + (q >> 1) * 64 + (q & 1) * 32 + (n0 & 31);
        E1f[chunk] = pack8(a0, a1, ia);
        E2f[chunk] = pack8(b0, b1, ib);

        a0 = na0; a1 = na1; b0 = nb0; b1 = nb1;
    }

    // block-reduce ddAcc (nonzero only on q==0 lanes)
    #pragma unroll
    for (int off = 1; off <= 32; off <<= 1) ddAcc += __shfl_xor(ddAcc, off);
    __shared__ float part[4];
    if (l == 0) part[w] = ddAcc;
    __syncthreads();
    if (tid == 0) diagPart[blockIdx.x] = part[0] + part[1] + part[2] + part[3];
}

// ---------------------------------------------------------------------------
// Kernel 2: fused GEMM + exp + row/col accumulation, fragment-major inputs.
// Grid (rt=8, ct=4, b=16) = 512 blocks (exactly 2/CU resident), 4 waves.
// Block tile: 256 rows x 512 cols. Wave: 64 rows (2 acc sets, A in 128 VGPRs)
// x all 512 cols. Each B-fragment feeds 2 MFMAs -> LDS traffic halved.
// B staged 32-cols-at-a-time (16 KB) via global_load_lds, double-buffered.
// ---------------------------------------------------------------------------
__global__ __launch_bounds__(256, 2) void gemm_kernel(
        const bf16x8* __restrict__ E1f, const uint4* __restrict__ E2f,
        float* __restrict__ colSum, float* __restrict__ rowSum) {
    __shared__ bf16x8 Bbuf[2][1024];   // 2 x 16 KB
    __shared__ float colLDS[2048];     // 4 per-wave slices of 512

    const int tid = threadIdx.x, w = tid >> 6, l = tid & 63;
    const int rt = blockIdx.x, ct = blockIdx.y, b = blockIdx.z;

    for (int i = l; i < 512; i += 64) colLDS[w * 512 + i] = 0.f;

    // A fragments: two 32-row tiles, fragment-major -> coalesced 1KB loads
    const bf16x8* Af0 = E1f + (size_t)b * 65536 + (size_t)(rt * 8 + w * 2) * 1024 + l;
    const bf16x8* Af1 = Af0 + 1024;
    bf16x8 af0[16], af1[16];
    #pragma unroll
    for (int kt = 0; kt < 16; ++kt) { af0[kt] = Af0[kt * 64]; af1[kt] = Af1[kt * 64]; }

    float rowAcc0[16], rowAcc1[16];
    #pragma unroll
    for (int r = 0; r < 16; ++r) { rowAcc0[r] = 0.f; rowAcc1[r] = 0.f; }

    // B chunks for this block's col range (fragment-major)
    const uint4* Bb = E2f + (size_t)b * 65536 + (size_t)ct * 16384 + l;

    // stage col-group cg into Bbuf[buf]; wave w stages kt = w*4 .. w*4+3
    auto stage = [&](int buf, int cg) {
        const uint4* src = Bb + (size_t)cg * 1024 + (w * 4) * 64;
        #pragma unroll
        for (int j = 0; j < 4; ++j)
            async_copy16(src + j * 64, &Bbuf[buf][(w * 4 + j) * 64]);
    };

    stage(0, 0);
    __syncthreads();

    for (int cg = 0; cg < 16; ++cg) {
        if (cg < 15) stage((cg + 1) & 1, cg + 1);

        const bf16x8* Bf = Bbuf[cg & 1];
        f32x16 acc0, acc1;
        #pragma unroll
        for (int r = 0; r < 16; ++r) { acc0[r] = 0.f; acc1[r] = 0.f; }

        #pragma unroll
        for (int kt = 0; kt < 16; ++kt) {
            bf16x8 bfrag = Bf[kt * 64 + l];
            acc0 = __builtin_amdgcn_mfma_f32_32x32x16_bf16(af0[kt], bfrag, acc0, 0, 0, 0);
            acc1 = __builtin_amdgcn_mfma_f32_32x32x16_bf16(af1[kt], bfrag, acc1, 0, 0, 0);
        }

        // epilogue: e = exp(10*s - 10)
        float p = 0.f;
        #pragma unroll
        for (int r = 0; r < 16; ++r) {
            float e0 = exp2f(fmaf(acc0[r], SCALE_L2E, -SCALE_L2E));
            float e1 = exp2f(fmaf(acc1[r], SCALE_L2E, -SCALE_L2E));
            rowAcc0[r] += e0;
            rowAcc1[r] += e1;
            p += e0 + e1;
        }
        p += __shfl_xor(p, 32);                    // fold 16-row halves
        if (l < 32) colLDS[w * 512 + cg * 32 + l] += p;   // wave-private
        __syncthreads();
    }

    // row sums: reduce across 32 column-lanes
    #pragma unroll
    for (int r = 0; r < 16; ++r) {
        #pragma unroll
        for (int off = 1; off <= 16; off <<= 1) {
            rowAcc0[r] += __shfl_xor(rowAcc0[r], off);
            rowAcc1[r] += __shfl_xor(rowAcc1[r], off);
        }
    }
    if ((l & 31) == 0) {
        // C/D layout: row = (r&3) + 8*(r>>2) + 4*(lane>>5)
        float* rs = rowSum + (size_t)b * 2048 + rt * 256 + w * 64 + 4 * (l >> 5);
        #pragma unroll
        for (int r = 0; r < 16; ++r) {
            const int rl = (r & 3) + 8 * (r >> 2);
            atomicAdd(&rs[rl], rowAcc0[r]);
            atomicAdd(&rs[rl + 32], rowAcc1[r]);
        }
    }

    // flush column sums (last loop barrier ordered colLDS writes)
    float* gcol = colSum + (size_t)b * 2048 + ct * 512;
    for (int i = tid; i < 512; i += 256) {
        float s = colLDS[i] + colLDS[512 + i] + colLDS[1024 + i] + colLDS[1536 + i];
        atomicAdd(&gcol[i], s);
    }
}

// ---------------------------------------------------------------------------
// Kernel 3a: sum of log over the 65536 row+col sums (colSum||rowSum buffer).
// ---------------------------------------------------------------------------
__global__ __launch_bounds__(256) void fin1_kernel(
        const float* __restrict__ red, float* __restrict__ scalars) {
    const int tid = threadIdx.x;
    float s = 0.f;
    #pragma unroll
    for (int k = 0; k < 4; ++k)
        s += logf(red[blockIdx.x * 1024 + k * 256 + tid]);
    #pragma unroll
    for (int off = 1; off <= 32; off <<= 1) s += __shfl_xor(s, off);
    __shared__ float part[4];
    if ((tid & 63) == 0) part[tid >> 6] = s;
    __syncthreads();
    if (tid == 0)
        atomicAdd(&scalars[0], part[0] + part[1] + part[2] + part[3]);
}

// ---------------------------------------------------------------------------
// Kernel 3b: reduce diagPart + finalize.
// out = (sum_logs - 2*diag)/32768 + 20   (fixed-max 10 per lse x 2 dirs)
// ---------------------------------------------------------------------------
__global__ __launch_bounds__(256) void fin2_kernel(
        const float* __restrict__ diagPart, const float* __restrict__ scalars,
        float* __restrict__ out) {
    const int tid = threadIdx.x;
    float d = 0.f;
    for (int i = tid; i < 1024; i += 256) d += diagPart[i];
    #pragma unroll
    for (int off = 1; off <= 32; off <<= 1) d += __shfl_xor(d, off);
    __shared__ float part[4];
    if ((tid & 63) == 0) part[tid >> 6] = d;
    __syncthreads();
    if (tid == 0) {
        const float diag = part[0] + part[1] + part[2] + part[3];
        out[0] = (scalars[0] - 2.0f * diag) / (float)NTOT + 20.0f;
    }
}

// ---------------------------------------------------------------------------
extern "C" void kernel_launch(void* const* d_in, const int* in_sizes, int n_in,
                              void* d_out, int out_size, void* d_ws, size_t ws_size,
                              hipStream_t stream) {
    const float* A = (const float*)d_in[0];
    const float* B = (const float*)d_in[1];

    char* w = (char*)d_ws;
    uint4* E1f = (uint4*)w;                                   // 16 MB
    uint4* E2f = (uint4*)(w + (size_t)16 * 1024 * 1024);      // 16 MB
    float* colSum = (float*)(w + (size_t)32 * 1024 * 1024);   // 32768 f
    float* rowSum = colSum + NTOT;                            // 32768 f
    float* scalars = rowSum + NTOT;                           // [logSum, pad]
    float* diagPart = scalars + 2;                            // 1024 f

    hipMemsetAsync(colSum, 0, (size_t)(2 * NTOT + 2) * 4, stream);

    hipLaunchKernelGGL(nrm_kernel, dim3(1024), dim3(256), 0, stream,
                       A, B, E1f, E2f, diagPart);
    hipLaunchKernelGGL(gemm_kernel, dim3(8, 4, 16), dim3(256), 0, stream,
                       (const bf16x8*)E1f, (const uint4*)E2f, colSum, rowSum);
    hipLaunchKernelGGL(fin1_kernel, dim3(64), dim3(256), 0, stream,
                       colSum, scalars);
    hipLaunchKernelGGL(fin2_kernel, dim3(1), dim3(256), 0, stream,
                       diagPart, scalars, (float*)d_out);
}